// Round 1
// baseline (979.290 us; speedup 1.0000x reference)
//
#include <hip/hip_runtime.h>
#include <hip/hip_bf16.h>
#include <cstddef>

#define N_NODES 20000
#define N_EDGES 320000
#define XDIM 128
#define H 256
#define LAYERS 4
#define G_GRAPHS 128
#define C_OUT 10
#define EPS_BN 1e-5f

// ---------------- degree histogram (by dst) ----------------
__global__ void hist_kernel(const int* __restrict__ dst, int* __restrict__ cnt, int E) {
    int e = blockIdx.x * blockDim.x + threadIdx.x;
    if (e < E) atomicAdd(&cnt[dst[e]], 1);
}

// ---------------- dinv = 1/sqrt(deg+1) ----------------
__global__ void dinv_kernel(const int* __restrict__ cnt, float* __restrict__ dinv, int N) {
    int n = blockIdx.x * blockDim.x + threadIdx.x;
    if (n < N) dinv[n] = 1.0f / sqrtf((float)cnt[n] + 1.0f);
}

// ---------------- exclusive scan of cnt -> rowstart[N+1] (single block) ----------------
__global__ void scan_kernel(const int* __restrict__ cnt, int* __restrict__ rowstart, int N) {
    __shared__ int partial[1024];
    int tid = threadIdx.x;
    int chunk = (N + 1023) / 1024;
    int start = tid * chunk;
    int lsum = 0;
    for (int i = 0; i < chunk; ++i) {
        int idx = start + i;
        if (idx < N) lsum += cnt[idx];
    }
    partial[tid] = lsum;
    __syncthreads();
    // Hillis-Steele inclusive scan
    for (int off = 1; off < 1024; off <<= 1) {
        int v = (tid >= off) ? partial[tid - off] : 0;
        __syncthreads();
        partial[tid] += v;
        __syncthreads();
    }
    int run = (tid == 0) ? 0 : partial[tid - 1];
    for (int i = 0; i < chunk; ++i) {
        int idx = start + i;
        if (idx < N) { rowstart[idx] = run; run += cnt[idx]; }
    }
    if (tid == 1023) rowstart[N] = partial[1023];
}

// ---------------- CSR fill: per-edge scatter of (src, weight) ----------------
__global__ void fill_kernel(const int* __restrict__ src, const int* __restrict__ dst,
                            const int* __restrict__ rowstart, int* __restrict__ cursor,
                            const float* __restrict__ dinv,
                            int* __restrict__ csr_src, float* __restrict__ csr_w, int E) {
    int e = blockIdx.x * blockDim.x + threadIdx.x;
    if (e < E) {
        int s = src[e], d = dst[e];
        int pos = rowstart[d] + atomicAdd(&cursor[d], 1);
        csr_src[pos] = s;
        csr_w[pos] = dinv[s] * dinv[d];
    }
}

// ---------------- fp32 SGEMM: C[M,Nn] = A[M,K] @ B[K,Nn] (+bias) ----------------
// 64x64 tile, BK=16, 256 threads, 4x4 microtile per thread.
#define BM 64
#define BNT 64
#define BK 16
__global__ __launch_bounds__(256) void sgemm_kernel(const float* __restrict__ A,
                                                    const float* __restrict__ B,
                                                    const float* __restrict__ bias,
                                                    float* __restrict__ C,
                                                    int M, int K, int Nn) {
    __shared__ float As[BK][BM];
    __shared__ float Bs[BK][BNT];
    int tid = threadIdx.x;
    int tr = tid >> 4;       // 0..15
    int tc = tid & 15;       // 0..15
    int bm = blockIdx.x * BM;
    int bn = blockIdx.y * BNT;
    float acc[4][4] = {};
    int ar = tid >> 2;        // 0..63   A-load row
    int ac = (tid & 3) * 4;   // 0,4,8,12 A-load col group
    int br = tid >> 4;        // 0..15   B-load row
    int bc = (tid & 15) * 4;  // 0..60   B-load col group

    for (int k0 = 0; k0 < K; k0 += BK) {
        int arow = bm + ar;
        float4 av;
        if (arow < M) av = *(const float4*)(A + (size_t)arow * K + k0 + ac);
        else          av = make_float4(0.f, 0.f, 0.f, 0.f);
        As[ac + 0][ar] = av.x;
        As[ac + 1][ar] = av.y;
        As[ac + 2][ar] = av.z;
        As[ac + 3][ar] = av.w;
        float4 bv = *(const float4*)(B + (size_t)(k0 + br) * Nn + bn + bc);
        *(float4*)&Bs[br][bc] = bv;
        __syncthreads();
#pragma unroll
        for (int kk = 0; kk < BK; ++kk) {
            float4 aq = *(const float4*)&As[kk][tr * 4];
            float4 bq = *(const float4*)&Bs[kk][tc * 4];
            acc[0][0] += aq.x * bq.x; acc[0][1] += aq.x * bq.y; acc[0][2] += aq.x * bq.z; acc[0][3] += aq.x * bq.w;
            acc[1][0] += aq.y * bq.x; acc[1][1] += aq.y * bq.y; acc[1][2] += aq.y * bq.z; acc[1][3] += aq.y * bq.w;
            acc[2][0] += aq.z * bq.x; acc[2][1] += aq.z * bq.y; acc[2][2] += aq.z * bq.z; acc[2][3] += aq.z * bq.w;
            acc[3][0] += aq.w * bq.x; acc[3][1] += aq.w * bq.y; acc[3][2] += aq.w * bq.z; acc[3][3] += aq.w * bq.w;
        }
        __syncthreads();
    }
    int col = bn + tc * 4;
    float bx = 0.f, by = 0.f, bz = 0.f, bw = 0.f;
    if (bias) { bx = bias[col]; by = bias[col + 1]; bz = bias[col + 2]; bw = bias[col + 3]; }
#pragma unroll
    for (int i = 0; i < 4; ++i) {
        int row = bm + tr * 4 + i;
        if (row < M) {
            float4 o;
            o.x = acc[i][0] + bx;
            o.y = acc[i][1] + by;
            o.z = acc[i][2] + bz;
            o.w = acc[i][3] + bw;
            *(float4*)(C + (size_t)row * Nn + col) = o;
        }
    }
}

// ---------------- aggregation: t2[n] = sum_in t[src]*w + t[n]*dinv^2 + convB ----------------
__global__ __launch_bounds__(256) void agg_kernel(const float* __restrict__ t,
                           const int* __restrict__ rowstart,
                           const int* __restrict__ csr_src,
                           const float* __restrict__ csr_w,
                           const float* __restrict__ dinv,
                           const float* __restrict__ convB,
                           float* __restrict__ out, int N) {
    int n = blockIdx.x;
    int h = threadIdx.x;  // 256
    int s = rowstart[n];
    int e = rowstart[n + 1];
    float acc = 0.f;
    int i = s;
    for (; i + 1 < e; i += 2) {
        int s0 = csr_src[i], s1 = csr_src[i + 1];
        float w0 = csr_w[i], w1 = csr_w[i + 1];
        float v0 = t[s0 * H + h];
        float v1 = t[s1 * H + h];
        acc += v0 * w0 + v1 * w1;
    }
    if (i < e) {
        int s0 = csr_src[i];
        acc += t[s0 * H + h] * csr_w[i];
    }
    float dn = dinv[n];
    acc += t[n * H + h] * (dn * dn) + convB[h];
    out[n * H + h] = acc;
}

// ---------------- per-channel sums / sumsq over [N,H] ----------------
__global__ void stats_kernel(const float* __restrict__ t, float* __restrict__ stats, int N) {
    int c = threadIdx.x;  // H
    float s = 0.f, s2 = 0.f;
    for (int r = blockIdx.x; r < N; r += gridDim.x) {
        float v = t[r * H + c];
        s += v;
        s2 += v * v;
    }
    atomicAdd(&stats[c], s);
    atomicAdd(&stats[H + c], s2);
}

// ---------------- BN (batch stats) + ReLU ----------------
__global__ void bnrelu_kernel(const float* __restrict__ t, const float* __restrict__ stats,
                              const float* __restrict__ gamma, const float* __restrict__ beta,
                              float* __restrict__ out, int N) {
    int c = threadIdx.x;  // H
    float invN = 1.0f / (float)N;
    float mean = stats[c] * invN;
    float var = stats[H + c] * invN - mean * mean;
    float sc = gamma[c] / sqrtf(var + EPS_BN);
    float sh = beta[c] - mean * sc;
    for (int r = blockIdx.x; r < N; r += gridDim.x) {
        float v = t[r * H + c];
        out[r * H + c] = fmaxf(v * sc + sh, 0.f);
    }
}

// ---------------- global mean pool (batch is sorted) ----------------
__global__ void pool_kernel(const float* __restrict__ h, const int* __restrict__ batch,
                            float* __restrict__ g, int N) {
    int gid = blockIdx.x;
    // lower_bound(batch, gid)
    int lo = 0, hi = N;
    while (lo < hi) { int mid = (lo + hi) >> 1; if (batch[mid] < gid) lo = mid + 1; else hi = mid; }
    int s = lo;
    lo = s; hi = N;
    while (lo < hi) { int mid = (lo + hi) >> 1; if (batch[mid] < gid + 1) lo = mid + 1; else hi = mid; }
    int e = lo;
    int c = threadIdx.x;  // H
    float acc = 0.f;
    for (int r = s; r < e; ++r) acc += h[r * H + c];
    float cntf = (float)(e - s);
    g[gid * H + c] = acc / fmaxf(cntf, 1.0f);
}

// ---------------- small FC: out[G,Nn] = in[G,K] @ W[K,Nn] + b ----------------
__global__ void fc_kernel(const float* __restrict__ in, const float* __restrict__ W,
                          const float* __restrict__ b, float* __restrict__ out,
                          int K, int Nn) {
    int g = blockIdx.x;
    int hc = threadIdx.x;
    if (hc >= Nn) return;
    const float* row = in + (size_t)g * K;
    float acc = b ? b[hc] : 0.f;
    for (int k = 0; k < K; ++k) acc += row[k] * W[(size_t)k * Nn + hc];
    out[(size_t)g * Nn + hc] = acc;
}

// ---------------- BN over small [G,H] (block per channel) ----------------
__global__ void bn_head_kernel(const float* __restrict__ in, const float* __restrict__ gamma,
                               const float* __restrict__ beta, float* __restrict__ out,
                               int Grows, int relu) {
    int c = blockIdx.x;   // H channels
    int r = threadIdx.x;  // Grows threads
    __shared__ float red[G_GRAPHS];
    float v = in[r * H + c];
    red[r] = v;
    __syncthreads();
    for (int off = G_GRAPHS / 2; off > 0; off >>= 1) {
        if (r < off) red[r] += red[r + off];
        __syncthreads();
    }
    float mean = red[0] / (float)Grows;
    __syncthreads();
    float d = v - mean;
    red[r] = d * d;
    __syncthreads();
    for (int off = G_GRAPHS / 2; off > 0; off >>= 1) {
        if (r < off) red[r] += red[r + off];
        __syncthreads();
    }
    float var = red[0] / (float)Grows;
    float y = gamma[c] * d / sqrtf(var + EPS_BN) + beta[c];
    if (relu) y = fmaxf(y, 0.f);
    out[r * H + c] = y;
}

extern "C" void kernel_launch(void* const* d_in, const int* in_sizes, int n_in,
                              void* d_out, int out_size, void* d_ws, size_t ws_size,
                              hipStream_t stream) {
    const float* x     = (const float*)d_in[0];
    const int*   edge  = (const int*)d_in[1];
    const int*   batch = (const int*)d_in[2];
    const float* encW  = (const float*)d_in[3];
    const float* encB  = (const float*)d_in[4];
    const float* convW = (const float*)d_in[5];
    const float* convB = (const float*)d_in[6];
    const float* bnG   = (const float*)d_in[7];
    const float* bnB   = (const float*)d_in[8];
    const float* fcW1  = (const float*)d_in[9];
    const float* fcB1  = (const float*)d_in[10];
    const float* fcG1  = (const float*)d_in[11];
    const float* fcBe1 = (const float*)d_in[12];
    const float* fcW2  = (const float*)d_in[13];
    const float* fcB2  = (const float*)d_in[14];
    const float* fcG2  = (const float*)d_in[15];
    const float* fcBe2 = (const float*)d_in[16];
    const float* fcW3  = (const float*)d_in[17];
    const float* fcB3  = (const float*)d_in[18];
    float* out = (float*)d_out;

    const int* srcIdx = edge;
    const int* dstIdx = edge + N_EDGES;

    float* w = (float*)d_ws;
    size_t off = 0;
    int*   cnt      = (int*)(w + off); off += N_NODES;        // 20000
    int*   cursor   = (int*)(w + off); off += N_NODES;        // 20000
    int*   rowstart = (int*)(w + off); off += 20016;          // N+1 padded
    float* dinv     = w + off;         off += N_NODES;
    int*   csr_src  = (int*)(w + off); off += N_EDGES;
    float* csr_w    = w + off;         off += N_EDGES;
    float* bnstats  = w + off;         off += LAYERS * 2 * H;
    float* hbuf     = w + off;         off += (size_t)N_NODES * H;
    float* tbuf     = w + off;         off += (size_t)N_NODES * H;
    float* t2buf    = w + off;         off += (size_t)N_NODES * H;
    float* gpool    = w + off;         off += G_GRAPHS * H;
    float* m1       = w + off;         off += G_GRAPHS * H;
    float* m2       = w + off;         off += G_GRAPHS * H;

    // zero-init (ws is re-poisoned before every call)
    hipMemsetAsync(cnt, 0, 2 * N_NODES * sizeof(int), stream);           // cnt + cursor
    hipMemsetAsync(bnstats, 0, LAYERS * 2 * H * sizeof(float), stream);

    // CSR build
    hist_kernel<<<(N_EDGES + 255) / 256, 256, 0, stream>>>(dstIdx, cnt, N_EDGES);
    dinv_kernel<<<(N_NODES + 255) / 256, 256, 0, stream>>>(cnt, dinv, N_NODES);
    scan_kernel<<<1, 1024, 0, stream>>>(cnt, rowstart, N_NODES);
    fill_kernel<<<(N_EDGES + 255) / 256, 256, 0, stream>>>(srcIdx, dstIdx, rowstart, cursor,
                                                           dinv, csr_src, csr_w, N_EDGES);

    // encoder: h = x @ encW + encB
    dim3 gridEnc((N_NODES + BM - 1) / BM, H / BNT);
    sgemm_kernel<<<gridEnc, 256, 0, stream>>>(x, encW, encB, hbuf, N_NODES, XDIM, H);

    // conv layers
    for (int l = 0; l < LAYERS; ++l) {
        dim3 gridC((N_NODES + BM - 1) / BM, H / BNT);
        sgemm_kernel<<<gridC, 256, 0, stream>>>(hbuf, convW + (size_t)l * H * H, nullptr,
                                                tbuf, N_NODES, H, H);
        agg_kernel<<<N_NODES, H, 0, stream>>>(tbuf, rowstart, csr_src, csr_w, dinv,
                                              convB + l * H, t2buf, N_NODES);
        stats_kernel<<<256, H, 0, stream>>>(t2buf, bnstats + l * 2 * H, N_NODES);
        bnrelu_kernel<<<512, H, 0, stream>>>(t2buf, bnstats + l * 2 * H,
                                             bnG + l * H, bnB + l * H, hbuf, N_NODES);
    }

    // global mean pool
    pool_kernel<<<G_GRAPHS, H, 0, stream>>>(hbuf, batch, gpool, N_NODES);

    // head
    fc_kernel<<<G_GRAPHS, H, 0, stream>>>(gpool, fcW1, fcB1, m1, H, H);
    bn_head_kernel<<<H, G_GRAPHS, 0, stream>>>(m1, fcG1, fcBe1, m1, G_GRAPHS, 1);
    fc_kernel<<<G_GRAPHS, H, 0, stream>>>(m1, fcW2, fcB2, m2, H, H);
    bn_head_kernel<<<H, G_GRAPHS, 0, stream>>>(m2, fcG2, fcBe2, m2, G_GRAPHS, 0);
    fc_kernel<<<G_GRAPHS, 64, 0, stream>>>(m2, fcW3, fcB3, out, H, C_OUT);
}

// Round 2
// 837.070 us; speedup vs baseline: 1.1699x; 1.1699x over previous
//
#include <hip/hip_runtime.h>
#include <hip/hip_bf16.h>
#include <cstddef>

#define N_NODES 20000
#define N_EDGES 320000
#define XDIM 128
#define H 256
#define LAYERS 4
#define G_GRAPHS 128
#define C_OUT 10
#define EPS_BN 1e-5f

// ---------------- degree histogram (by dst) ----------------
__global__ void hist_kernel(const int* __restrict__ dst, int* __restrict__ cnt, int E) {
    int e = blockIdx.x * blockDim.x + threadIdx.x;
    if (e < E) atomicAdd(&cnt[dst[e]], 1);
}

// ---------------- dinv = 1/sqrt(deg+1) ----------------
__global__ void dinv_kernel(const int* __restrict__ cnt, float* __restrict__ dinv, int N) {
    int n = blockIdx.x * blockDim.x + threadIdx.x;
    if (n < N) dinv[n] = 1.0f / sqrtf((float)cnt[n] + 1.0f);
}

// ---------------- exclusive scan of cnt -> rowstart[N+1] (single block) ----------------
__global__ void scan_kernel(const int* __restrict__ cnt, int* __restrict__ rowstart, int N) {
    __shared__ int partial[1024];
    int tid = threadIdx.x;
    int chunk = (N + 1023) / 1024;
    int start = tid * chunk;
    int lsum = 0;
    for (int i = 0; i < chunk; ++i) {
        int idx = start + i;
        if (idx < N) lsum += cnt[idx];
    }
    partial[tid] = lsum;
    __syncthreads();
    // Hillis-Steele inclusive scan
    for (int off = 1; off < 1024; off <<= 1) {
        int v = (tid >= off) ? partial[tid - off] : 0;
        __syncthreads();
        partial[tid] += v;
        __syncthreads();
    }
    int run = (tid == 0) ? 0 : partial[tid - 1];
    for (int i = 0; i < chunk; ++i) {
        int idx = start + i;
        if (idx < N) { rowstart[idx] = run; run += cnt[idx]; }
    }
    if (tid == 1023) rowstart[N] = partial[1023];
}

// ---------------- CSR fill: per-edge scatter of (src, weight) ----------------
__global__ void fill_kernel(const int* __restrict__ src, const int* __restrict__ dst,
                            const int* __restrict__ rowstart, int* __restrict__ cursor,
                            const float* __restrict__ dinv,
                            int* __restrict__ csr_src, float* __restrict__ csr_w, int E) {
    int e = blockIdx.x * blockDim.x + threadIdx.x;
    if (e < E) {
        int s = src[e], d = dst[e];
        int pos = rowstart[d] + atomicAdd(&cursor[d], 1);
        csr_src[pos] = s;
        csr_w[pos] = dinv[s] * dinv[d];
    }
}

// ---------------- fp32 SGEMM: C[M,Nn] = A[M,K] @ B[K,Nn] (+bias) ----------------
// 64x64 tile, BK=16, 256 threads, 4x4 microtile per thread.
#define BM 64
#define BNT 64
#define BK 16
__global__ __launch_bounds__(256) void sgemm_kernel(const float* __restrict__ A,
                                                    const float* __restrict__ B,
                                                    const float* __restrict__ bias,
                                                    float* __restrict__ C,
                                                    int M, int K, int Nn) {
    __shared__ float As[BK][BM];
    __shared__ float Bs[BK][BNT];
    int tid = threadIdx.x;
    int tr = tid >> 4;       // 0..15
    int tc = tid & 15;       // 0..15
    int bm = blockIdx.x * BM;
    int bn = blockIdx.y * BNT;
    float acc[4][4] = {};
    int ar = tid >> 2;        // 0..63   A-load row
    int ac = (tid & 3) * 4;   // 0,4,8,12 A-load col group
    int br = tid >> 4;        // 0..15   B-load row
    int bc = (tid & 15) * 4;  // 0..60   B-load col group

    for (int k0 = 0; k0 < K; k0 += BK) {
        int arow = bm + ar;
        float4 av;
        if (arow < M) av = *(const float4*)(A + (size_t)arow * K + k0 + ac);
        else          av = make_float4(0.f, 0.f, 0.f, 0.f);
        As[ac + 0][ar] = av.x;
        As[ac + 1][ar] = av.y;
        As[ac + 2][ar] = av.z;
        As[ac + 3][ar] = av.w;
        float4 bv = *(const float4*)(B + (size_t)(k0 + br) * Nn + bn + bc);
        *(float4*)&Bs[br][bc] = bv;
        __syncthreads();
#pragma unroll
        for (int kk = 0; kk < BK; ++kk) {
            float4 aq = *(const float4*)&As[kk][tr * 4];
            float4 bq = *(const float4*)&Bs[kk][tc * 4];
            acc[0][0] += aq.x * bq.x; acc[0][1] += aq.x * bq.y; acc[0][2] += aq.x * bq.z; acc[0][3] += aq.x * bq.w;
            acc[1][0] += aq.y * bq.x; acc[1][1] += aq.y * bq.y; acc[1][2] += aq.y * bq.z; acc[1][3] += aq.y * bq.w;
            acc[2][0] += aq.z * bq.x; acc[2][1] += aq.z * bq.y; acc[2][2] += aq.z * bq.z; acc[2][3] += aq.z * bq.w;
            acc[3][0] += aq.w * bq.x; acc[3][1] += aq.w * bq.y; acc[3][2] += aq.w * bq.z; acc[3][3] += aq.w * bq.w;
        }
        __syncthreads();
    }
    int col = bn + tc * 4;
    float bx = 0.f, by = 0.f, bz = 0.f, bw = 0.f;
    if (bias) { bx = bias[col]; by = bias[col + 1]; bz = bias[col + 2]; bw = bias[col + 3]; }
#pragma unroll
    for (int i = 0; i < 4; ++i) {
        int row = bm + tr * 4 + i;
        if (row < M) {
            float4 o;
            o.x = acc[i][0] + bx;
            o.y = acc[i][1] + by;
            o.z = acc[i][2] + bz;
            o.w = acc[i][3] + bw;
            *(float4*)(C + (size_t)row * Nn + col) = o;
        }
    }
}

// ---------------- aggregation: t2[n] = sum_in t[src]*w + t[n]*dinv^2 + convB ----------------
__global__ __launch_bounds__(256) void agg_kernel(const float* __restrict__ t,
                           const int* __restrict__ rowstart,
                           const int* __restrict__ csr_src,
                           const float* __restrict__ csr_w,
                           const float* __restrict__ dinv,
                           const float* __restrict__ convB,
                           float* __restrict__ out, int N) {
    int n = blockIdx.x;
    int h = threadIdx.x;  // 256
    int s = rowstart[n];
    int e = rowstart[n + 1];
    float acc = 0.f;
    int i = s;
    for (; i + 1 < e; i += 2) {
        int s0 = csr_src[i], s1 = csr_src[i + 1];
        float w0 = csr_w[i], w1 = csr_w[i + 1];
        float v0 = t[s0 * H + h];
        float v1 = t[s1 * H + h];
        acc += v0 * w0 + v1 * w1;
    }
    if (i < e) {
        int s0 = csr_src[i];
        acc += t[s0 * H + h] * csr_w[i];
    }
    float dn = dinv[n];
    acc += t[n * H + h] * (dn * dn) + convB[h];
    out[n * H + h] = acc;
}

// ---------------- per-channel sums / sumsq over [N,H] ----------------
__global__ void stats_kernel(const float* __restrict__ t, float* __restrict__ stats, int N) {
    int c = threadIdx.x;  // H
    float s = 0.f, s2 = 0.f;
    for (int r = blockIdx.x; r < N; r += gridDim.x) {
        float v = t[r * H + c];
        s += v;
        s2 += v * v;
    }
    atomicAdd(&stats[c], s);
    atomicAdd(&stats[H + c], s2);
}

// ---------------- BN (batch stats) + ReLU ----------------
__global__ void bnrelu_kernel(const float* __restrict__ t, const float* __restrict__ stats,
                              const float* __restrict__ gamma, const float* __restrict__ beta,
                              float* __restrict__ out, int N) {
    int c = threadIdx.x;  // H
    float invN = 1.0f / (float)N;
    float mean = stats[c] * invN;
    float var = stats[H + c] * invN - mean * mean;
    float sc = gamma[c] / sqrtf(var + EPS_BN);
    float sh = beta[c] - mean * sc;
    for (int r = blockIdx.x; r < N; r += gridDim.x) {
        float v = t[r * H + c];
        out[r * H + c] = fmaxf(v * sc + sh, 0.f);
    }
}

// ---------------- global mean pool (batch is sorted) ----------------
__global__ void pool_kernel(const float* __restrict__ h, const int* __restrict__ batch,
                            float* __restrict__ g, int N) {
    int gid = blockIdx.x;
    // lower_bound(batch, gid)
    int lo = 0, hi = N;
    while (lo < hi) { int mid = (lo + hi) >> 1; if (batch[mid] < gid) lo = mid + 1; else hi = mid; }
    int s = lo;
    lo = s; hi = N;
    while (lo < hi) { int mid = (lo + hi) >> 1; if (batch[mid] < gid + 1) lo = mid + 1; else hi = mid; }
    int e = lo;
    int c = threadIdx.x;  // H
    float acc = 0.f;
    for (int r = s; r < e; ++r) acc += h[r * H + c];
    float cntf = (float)(e - s);
    g[gid * H + c] = acc / fmaxf(cntf, 1.0f);
}

// ---------------- FC with compile-time K/NN: LDS-staged row, fully unrolled ----------------
template <int K, int NN>
__global__ __launch_bounds__(256) void fc_lds_kernel(const float* __restrict__ in,
                                                     const float* __restrict__ W,
                                                     const float* __restrict__ b,
                                                     float* __restrict__ out) {
    __shared__ float row[K];
    int g = blockIdx.x;
    for (int k = threadIdx.x; k < K; k += 256) row[k] = in[(size_t)g * K + k];
    __syncthreads();
    int hc = threadIdx.x;
    if (hc < NN) {
        float acc = b[hc];
#pragma unroll
        for (int k = 0; k < K; ++k) acc += row[k] * W[k * NN + hc];
        out[(size_t)g * NN + hc] = acc;
    }
}

// ---------------- final FC: out[G,C] = in[G,H] @ W[H,C] + b, flat threads ----------------
__global__ void fc_out_kernel(const float* __restrict__ in, const float* __restrict__ W,
                              const float* __restrict__ b, float* __restrict__ out) {
    int t = blockIdx.x * blockDim.x + threadIdx.x;
    if (t >= G_GRAPHS * C_OUT) return;
    int g = t / C_OUT, c = t % C_OUT;
    float acc = b[c];
#pragma unroll 16
    for (int k = 0; k < H; ++k) acc += in[(size_t)g * H + k] * W[k * C_OUT + c];
    out[t] = acc;
}

// ---------------- BN over small [G,H] (block per channel) ----------------
__global__ void bn_head_kernel(const float* __restrict__ in, const float* __restrict__ gamma,
                               const float* __restrict__ beta, float* __restrict__ out,
                               int Grows, int relu) {
    int c = blockIdx.x;   // H channels
    int r = threadIdx.x;  // Grows threads
    __shared__ float red[G_GRAPHS];
    float v = in[r * H + c];
    red[r] = v;
    __syncthreads();
    for (int off = G_GRAPHS / 2; off > 0; off >>= 1) {
        if (r < off) red[r] += red[r + off];
        __syncthreads();
    }
    float mean = red[0] / (float)Grows;
    __syncthreads();
    float d = v - mean;
    red[r] = d * d;
    __syncthreads();
    for (int off = G_GRAPHS / 2; off > 0; off >>= 1) {
        if (r < off) red[r] += red[r + off];
        __syncthreads();
    }
    float var = red[0] / (float)Grows;
    float y = gamma[c] * d / sqrtf(var + EPS_BN) + beta[c];
    if (relu) y = fmaxf(y, 0.f);
    out[r * H + c] = y;
}

extern "C" void kernel_launch(void* const* d_in, const int* in_sizes, int n_in,
                              void* d_out, int out_size, void* d_ws, size_t ws_size,
                              hipStream_t stream) {
    const float* x     = (const float*)d_in[0];
    const int*   edge  = (const int*)d_in[1];
    const int*   batch = (const int*)d_in[2];
    const float* encW  = (const float*)d_in[3];
    const float* encB  = (const float*)d_in[4];
    const float* convW = (const float*)d_in[5];
    const float* convB = (const float*)d_in[6];
    const float* bnG   = (const float*)d_in[7];
    const float* bnB   = (const float*)d_in[8];
    const float* fcW1  = (const float*)d_in[9];
    const float* fcB1  = (const float*)d_in[10];
    const float* fcG1  = (const float*)d_in[11];
    const float* fcBe1 = (const float*)d_in[12];
    const float* fcW2  = (const float*)d_in[13];
    const float* fcB2  = (const float*)d_in[14];
    const float* fcG2  = (const float*)d_in[15];
    const float* fcBe2 = (const float*)d_in[16];
    const float* fcW3  = (const float*)d_in[17];
    const float* fcB3  = (const float*)d_in[18];
    float* out = (float*)d_out;

    const int* srcIdx = edge;
    const int* dstIdx = edge + N_EDGES;

    float* w = (float*)d_ws;
    size_t off = 0;
    int*   cnt      = (int*)(w + off); off += N_NODES;        // 20000
    int*   cursor   = (int*)(w + off); off += N_NODES;        // 20000
    int*   rowstart = (int*)(w + off); off += 20016;          // N+1 padded
    float* dinv     = w + off;         off += N_NODES;
    int*   csr_src  = (int*)(w + off); off += N_EDGES;
    float* csr_w    = w + off;         off += N_EDGES;
    float* bnstats  = w + off;         off += LAYERS * 2 * H;
    float* hbuf     = w + off;         off += (size_t)N_NODES * H;
    float* tbuf     = w + off;         off += (size_t)N_NODES * H;
    float* t2buf    = w + off;         off += (size_t)N_NODES * H;
    float* gpool    = w + off;         off += G_GRAPHS * H;
    float* m1       = w + off;         off += G_GRAPHS * H;
    float* m2       = w + off;         off += G_GRAPHS * H;

    // zero-init (ws is re-poisoned before every call)
    hipMemsetAsync(cnt, 0, 2 * N_NODES * sizeof(int), stream);           // cnt + cursor
    hipMemsetAsync(bnstats, 0, LAYERS * 2 * H * sizeof(float), stream);

    // CSR build
    hist_kernel<<<(N_EDGES + 255) / 256, 256, 0, stream>>>(dstIdx, cnt, N_EDGES);
    dinv_kernel<<<(N_NODES + 255) / 256, 256, 0, stream>>>(cnt, dinv, N_NODES);
    scan_kernel<<<1, 1024, 0, stream>>>(cnt, rowstart, N_NODES);
    fill_kernel<<<(N_EDGES + 255) / 256, 256, 0, stream>>>(srcIdx, dstIdx, rowstart, cursor,
                                                           dinv, csr_src, csr_w, N_EDGES);

    // encoder: h = x @ encW + encB
    dim3 gridEnc((N_NODES + BM - 1) / BM, H / BNT);
    sgemm_kernel<<<gridEnc, 256, 0, stream>>>(x, encW, encB, hbuf, N_NODES, XDIM, H);

    // conv layers
    for (int l = 0; l < LAYERS; ++l) {
        dim3 gridC((N_NODES + BM - 1) / BM, H / BNT);
        sgemm_kernel<<<gridC, 256, 0, stream>>>(hbuf, convW + (size_t)l * H * H, nullptr,
                                                tbuf, N_NODES, H, H);
        agg_kernel<<<N_NODES, H, 0, stream>>>(tbuf, rowstart, csr_src, csr_w, dinv,
                                              convB + l * H, t2buf, N_NODES);
        stats_kernel<<<256, H, 0, stream>>>(t2buf, bnstats + l * 2 * H, N_NODES);
        bnrelu_kernel<<<512, H, 0, stream>>>(t2buf, bnstats + l * 2 * H,
                                             bnG + l * H, bnB + l * H, hbuf, N_NODES);
    }

    // global mean pool
    pool_kernel<<<G_GRAPHS, H, 0, stream>>>(hbuf, batch, gpool, N_NODES);

    // head: Linear -> BN+ReLU -> Linear -> BN -> Linear
    fc_lds_kernel<H, H><<<G_GRAPHS, 256, 0, stream>>>(gpool, fcW1, fcB1, m1);
    bn_head_kernel<<<H, G_GRAPHS, 0, stream>>>(m1, fcG1, fcBe1, m1, G_GRAPHS, 1);
    fc_lds_kernel<H, H><<<G_GRAPHS, 256, 0, stream>>>(m1, fcW2, fcB2, m2);
    bn_head_kernel<<<H, G_GRAPHS, 0, stream>>>(m2, fcG2, fcBe2, m2, G_GRAPHS, 0);
    fc_out_kernel<<<(G_GRAPHS * C_OUT + 255) / 256, 256, 0, stream>>>(m2, fcW3, fcB3, out);
}

// Round 3
// 636.214 us; speedup vs baseline: 1.5392x; 1.3157x over previous
//
#include <hip/hip_runtime.h>
#include <hip/hip_bf16.h>
#include <cstddef>

#define N_NODES 20000
#define N_EDGES 320000
#define XDIM 128
#define H 256
#define LAYERS 4
#define G_GRAPHS 128
#define C_OUT 10
#define EPS_BN 1e-5f

typedef __attribute__((ext_vector_type(8))) short short8;
typedef __attribute__((ext_vector_type(4))) float f32x4;

// ---------------- degree histogram (by dst) ----------------
__global__ void hist_kernel(const int* __restrict__ dst, int* __restrict__ cnt, int E) {
    int e = blockIdx.x * blockDim.x + threadIdx.x;
    if (e < E) atomicAdd(&cnt[dst[e]], 1);
}

// ---------------- dinv = 1/sqrt(deg+1) ----------------
__global__ void dinv_kernel(const int* __restrict__ cnt, float* __restrict__ dinv, int N) {
    int n = blockIdx.x * blockDim.x + threadIdx.x;
    if (n < N) dinv[n] = 1.0f / sqrtf((float)cnt[n] + 1.0f);
}

// ---------------- exclusive scan of cnt -> rowstart[N+1] (single block) ----------------
__global__ void scan_kernel(const int* __restrict__ cnt, int* __restrict__ rowstart, int N) {
    __shared__ int partial[1024];
    int tid = threadIdx.x;
    int chunk = (N + 1023) / 1024;
    int start = tid * chunk;
    int lsum = 0;
    for (int i = 0; i < chunk; ++i) {
        int idx = start + i;
        if (idx < N) lsum += cnt[idx];
    }
    partial[tid] = lsum;
    __syncthreads();
    for (int off = 1; off < 1024; off <<= 1) {
        int v = (tid >= off) ? partial[tid - off] : 0;
        __syncthreads();
        partial[tid] += v;
        __syncthreads();
    }
    int run = (tid == 0) ? 0 : partial[tid - 1];
    for (int i = 0; i < chunk; ++i) {
        int idx = start + i;
        if (idx < N) { rowstart[idx] = run; run += cnt[idx]; }
    }
    if (tid == 1023) rowstart[N] = partial[1023];
}

// ---------------- CSR fill ----------------
__global__ void fill_kernel(const int* __restrict__ src, const int* __restrict__ dst,
                            const int* __restrict__ rowstart, int* __restrict__ cursor,
                            const float* __restrict__ dinv,
                            int* __restrict__ csr_src, float* __restrict__ csr_w, int E) {
    int e = blockIdx.x * blockDim.x + threadIdx.x;
    if (e < E) {
        int s = src[e], d = dst[e];
        int pos = rowstart[d] + atomicAdd(&cursor[d], 1);
        csr_src[pos] = s;
        csr_w[pos] = dinv[s] * dinv[d];
    }
}

// ---------------- fp32 -> bf16 cast ----------------
__global__ void cast_bf16_kernel(const float* __restrict__ in, __hip_bfloat16* __restrict__ out, int n) {
    int i = blockIdx.x * blockDim.x + threadIdx.x;
    if (i < n) out[i] = __float2bfloat16(in[i]);
}

// ---------------- transpose+cast: out[c*R+r] = in[r*C+c], per layer chunk ----------------
__global__ void tcast_kernel(const float* __restrict__ in, __hip_bfloat16* __restrict__ out,
                             int R, int C, int layers) {
    int i = blockIdx.x * blockDim.x + threadIdx.x;
    int per = R * C;
    if (i >= per * layers) return;
    int l = i / per, rem = i - l * per;
    int r = rem / C, c = rem - r * C;
    out[(size_t)l * per + (size_t)c * R + r] = __float2bfloat16(in[i]);
}

// ---------------- bf16 MFMA GEMM: C[M,Nn] = A[M,K] @ BT[Nn,K]^T (+bias), bf16 out ----------
// 128x128 tile, 256 threads = 4 waves (2x2 of 64x64), 16x16x32 MFMA, XOR k-slot swizzle.
template <int K>
__global__ __launch_bounds__(256) void gemm_bf16_kernel(
    const __hip_bfloat16* __restrict__ A,   // [M,K] row-major
    const __hip_bfloat16* __restrict__ BT,  // [Nn,K] row-major (B transposed)
    const float* __restrict__ bias,         // [Nn] or nullptr
    __hip_bfloat16* __restrict__ Cbf,       // [M,Nn]
    int M, int Nn) {
    __shared__ short As[128 * 32];  // 8 KB
    __shared__ short Bs[128 * 32];  // 8 KB
    const short* Ash = (const short*)A;
    const short* Bsh = (const short*)BT;
    int tid = threadIdx.x;
    int lane = tid & 63;
    int wave = tid >> 6;
    int quad = lane >> 4;
    int lr = lane & 15;
    int wm = (wave & 1) * 64;
    int wn = (wave >> 1) * 64;
    int Mblk = blockIdx.x * 128;
    int Nblk = blockIdx.y * 128;

    f32x4 acc[4][4];
#pragma unroll
    for (int i = 0; i < 4; ++i)
#pragma unroll
        for (int j = 0; j < 4; ++j) acc[i][j] = (f32x4){0.f, 0.f, 0.f, 0.f};

    for (int k0 = 0; k0 < K; k0 += 32) {
        // stage A-tile and B-tile: 2 x 256 threads x 16B each
#pragma unroll
        for (int i = 0; i < 2; ++i) {
            int s = i * 256 + tid;              // 0..511
            int row = s >> 2;                   // 0..127
            int qs = s & 3;                     // LDS k-slot
            int qg = qs ^ ((row >> 1) & 3);     // swizzled global k-chunk
            int arow = Mblk + row; if (arow >= M) arow = M - 1;
            *(float4*)&As[row * 32 + qs * 8] =
                *(const float4*)(Ash + (size_t)arow * K + k0 + qg * 8);
            int brow = Nblk + row;              // Nn is a multiple of 128
            *(float4*)&Bs[row * 32 + qs * 8] =
                *(const float4*)(Bsh + (size_t)brow * K + k0 + qg * 8);
        }
        __syncthreads();
        short8 af[4], bfr[4];
#pragma unroll
        for (int mi = 0; mi < 4; ++mi) {
            int r = wm + mi * 16 + lr;
            af[mi] = *(const short8*)&As[r * 32 + (quad ^ ((r >> 1) & 3)) * 8];
        }
#pragma unroll
        for (int ni = 0; ni < 4; ++ni) {
            int r = wn + ni * 16 + lr;
            bfr[ni] = *(const short8*)&Bs[r * 32 + (quad ^ ((r >> 1) & 3)) * 8];
        }
#pragma unroll
        for (int mi = 0; mi < 4; ++mi)
#pragma unroll
            for (int ni = 0; ni < 4; ++ni)
                acc[mi][ni] = __builtin_amdgcn_mfma_f32_16x16x32_bf16(af[mi], bfr[ni], acc[mi][ni], 0, 0, 0);
        __syncthreads();
    }
    // epilogue: C/D layout col=lane&15, row=quad*4+reg
#pragma unroll
    for (int mi = 0; mi < 4; ++mi) {
#pragma unroll
        for (int r = 0; r < 4; ++r) {
            int m = Mblk + wm + mi * 16 + quad * 4 + r;
            if (m < M) {
#pragma unroll
                for (int ni = 0; ni < 4; ++ni) {
                    int n = Nblk + wn + ni * 16 + lr;
                    float v = acc[mi][ni][r];
                    if (bias) v += bias[n];
                    Cbf[(size_t)m * Nn + n] = __float2bfloat16(v);
                }
            }
        }
    }
}

// ---------------- aggregation: t2[n] = sum_in t[src]*w + t[n]*dinv^2 + convB (bf16 gather) ----
__global__ __launch_bounds__(256) void agg_kernel(const __hip_bfloat16* __restrict__ t,
                           const int* __restrict__ rowstart,
                           const int* __restrict__ csr_src,
                           const float* __restrict__ csr_w,
                           const float* __restrict__ dinv,
                           const float* __restrict__ convB,
                           float* __restrict__ out, int N) {
    int n = blockIdx.x;
    int h = threadIdx.x;  // 256
    int s = rowstart[n];
    int e = rowstart[n + 1];
    float acc = 0.f;
    int i = s;
    for (; i + 1 < e; i += 2) {
        int s0 = csr_src[i], s1 = csr_src[i + 1];
        float w0 = csr_w[i], w1 = csr_w[i + 1];
        float v0 = __bfloat162float(t[(size_t)s0 * H + h]);
        float v1 = __bfloat162float(t[(size_t)s1 * H + h]);
        acc += v0 * w0 + v1 * w1;
    }
    if (i < e) {
        int s0 = csr_src[i];
        acc += __bfloat162float(t[(size_t)s0 * H + h]) * csr_w[i];
    }
    float dn = dinv[n];
    acc += __bfloat162float(t[(size_t)n * H + h]) * (dn * dn) + convB[h];
    out[(size_t)n * H + h] = acc;
}

// ---------------- per-channel sums / sumsq over [N,H] ----------------
__global__ void stats_kernel(const float* __restrict__ t, float* __restrict__ stats, int N) {
    int c = threadIdx.x;  // H
    float s = 0.f, s2 = 0.f;
    for (int r = blockIdx.x; r < N; r += gridDim.x) {
        float v = t[(size_t)r * H + c];
        s += v;
        s2 += v * v;
    }
    atomicAdd(&stats[c], s);
    atomicAdd(&stats[H + c], s2);
}

// ---------------- BN (batch stats) + ReLU -> bf16 ----------------
__global__ void bnrelu_kernel(const float* __restrict__ t, const float* __restrict__ stats,
                              const float* __restrict__ gamma, const float* __restrict__ beta,
                              __hip_bfloat16* __restrict__ out, int N) {
    int c = threadIdx.x;  // H
    float invN = 1.0f / (float)N;
    float mean = stats[c] * invN;
    float var = stats[H + c] * invN - mean * mean;
    float sc = gamma[c] / sqrtf(var + EPS_BN);
    float sh = beta[c] - mean * sc;
    for (int r = blockIdx.x; r < N; r += gridDim.x) {
        float v = t[(size_t)r * H + c];
        out[(size_t)r * H + c] = __float2bfloat16(fmaxf(v * sc + sh, 0.f));
    }
}

// ---------------- global mean pool (batch is sorted), bf16 in -> fp32 out ----------------
__global__ void pool_kernel(const __hip_bfloat16* __restrict__ h, const int* __restrict__ batch,
                            float* __restrict__ g, int N) {
    int gid = blockIdx.x;
    int lo = 0, hi = N;
    while (lo < hi) { int mid = (lo + hi) >> 1; if (batch[mid] < gid) lo = mid + 1; else hi = mid; }
    int s = lo;
    lo = s; hi = N;
    while (lo < hi) { int mid = (lo + hi) >> 1; if (batch[mid] < gid + 1) lo = mid + 1; else hi = mid; }
    int e = lo;
    int c = threadIdx.x;  // H
    float acc = 0.f;
    for (int r = s; r < e; ++r) acc += __bfloat162float(h[(size_t)r * H + c]);
    float cntf = (float)(e - s);
    g[gid * H + c] = acc / fmaxf(cntf, 1.0f);
}

// ---------------- FC with compile-time K/NN: LDS-staged row, fully unrolled ----------------
template <int K, int NN>
__global__ __launch_bounds__(256) void fc_lds_kernel(const float* __restrict__ in,
                                                     const float* __restrict__ W,
                                                     const float* __restrict__ b,
                                                     float* __restrict__ out) {
    __shared__ float row[K];
    int g = blockIdx.x;
    for (int k = threadIdx.x; k < K; k += 256) row[k] = in[(size_t)g * K + k];
    __syncthreads();
    int hc = threadIdx.x;
    if (hc < NN) {
        float acc = b[hc];
#pragma unroll
        for (int k = 0; k < K; ++k) acc += row[k] * W[k * NN + hc];
        out[(size_t)g * NN + hc] = acc;
    }
}

// ---------------- final FC: out[G,C] = in[G,H] @ W[H,C] + b ----------------
__global__ void fc_out_kernel(const float* __restrict__ in, const float* __restrict__ W,
                              const float* __restrict__ b, float* __restrict__ out) {
    int t = blockIdx.x * blockDim.x + threadIdx.x;
    if (t >= G_GRAPHS * C_OUT) return;
    int g = t / C_OUT, c = t % C_OUT;
    float acc = b[c];
#pragma unroll 16
    for (int k = 0; k < H; ++k) acc += in[(size_t)g * H + k] * W[k * C_OUT + c];
    out[t] = acc;
}

// ---------------- BN over small [G,H] (block per channel) ----------------
__global__ void bn_head_kernel(const float* __restrict__ in, const float* __restrict__ gamma,
                               const float* __restrict__ beta, float* __restrict__ out,
                               int Grows, int relu) {
    int c = blockIdx.x;
    int r = threadIdx.x;
    __shared__ float red[G_GRAPHS];
    float v = in[r * H + c];
    red[r] = v;
    __syncthreads();
    for (int off = G_GRAPHS / 2; off > 0; off >>= 1) {
        if (r < off) red[r] += red[r + off];
        __syncthreads();
    }
    float mean = red[0] / (float)Grows;
    __syncthreads();
    float d = v - mean;
    red[r] = d * d;
    __syncthreads();
    for (int off = G_GRAPHS / 2; off > 0; off >>= 1) {
        if (r < off) red[r] += red[r + off];
        __syncthreads();
    }
    float var = red[0] / (float)Grows;
    float y = gamma[c] * d / sqrtf(var + EPS_BN) + beta[c];
    if (relu) y = fmaxf(y, 0.f);
    out[r * H + c] = y;
}

extern "C" void kernel_launch(void* const* d_in, const int* in_sizes, int n_in,
                              void* d_out, int out_size, void* d_ws, size_t ws_size,
                              hipStream_t stream) {
    const float* x     = (const float*)d_in[0];
    const int*   edge  = (const int*)d_in[1];
    const int*   batch = (const int*)d_in[2];
    const float* encW  = (const float*)d_in[3];
    const float* encB  = (const float*)d_in[4];
    const float* convW = (const float*)d_in[5];
    const float* convB = (const float*)d_in[6];
    const float* bnG   = (const float*)d_in[7];
    const float* bnB   = (const float*)d_in[8];
    const float* fcW1  = (const float*)d_in[9];
    const float* fcB1  = (const float*)d_in[10];
    const float* fcG1  = (const float*)d_in[11];
    const float* fcBe1 = (const float*)d_in[12];
    const float* fcW2  = (const float*)d_in[13];
    const float* fcB2  = (const float*)d_in[14];
    const float* fcG2  = (const float*)d_in[15];
    const float* fcBe2 = (const float*)d_in[16];
    const float* fcW3  = (const float*)d_in[17];
    const float* fcB3  = (const float*)d_in[18];
    float* out = (float*)d_out;

    const int* srcIdx = edge;
    const int* dstIdx = edge + N_EDGES;

    char* base = (char*)d_ws;
    size_t off = 0;
    auto alloc = [&](size_t bytes) -> void* {
        void* p = base + off;
        off = (off + bytes + 255) & ~(size_t)255;
        return p;
    };
    int*   cnt      = (int*)alloc(N_NODES * 4);
    int*   cursor   = (int*)alloc(N_NODES * 4);
    int*   rowstart = (int*)alloc((N_NODES + 1) * 4);
    float* dinv     = (float*)alloc(N_NODES * 4);
    int*   csr_src  = (int*)alloc(N_EDGES * 4);
    float* csr_w    = (float*)alloc(N_EDGES * 4);
    float* bnstats  = (float*)alloc(LAYERS * 2 * H * 4);
    __hip_bfloat16* xbf    = (__hip_bfloat16*)alloc((size_t)N_NODES * XDIM * 2);
    __hip_bfloat16* encWT  = (__hip_bfloat16*)alloc((size_t)H * XDIM * 2);
    __hip_bfloat16* convWT = (__hip_bfloat16*)alloc((size_t)LAYERS * H * H * 2);
    __hip_bfloat16* hbf    = (__hip_bfloat16*)alloc((size_t)N_NODES * H * 2);
    __hip_bfloat16* tbf    = (__hip_bfloat16*)alloc((size_t)N_NODES * H * 2);
    float* t2buf = (float*)alloc((size_t)N_NODES * H * 4);
    float* gpool = (float*)alloc(G_GRAPHS * H * 4);
    float* m1    = (float*)alloc(G_GRAPHS * H * 4);
    float* m2    = (float*)alloc(G_GRAPHS * H * 4);

    // zero-init
    hipMemsetAsync(cnt, 0, N_NODES * 4, stream);
    hipMemsetAsync(cursor, 0, N_NODES * 4, stream);
    hipMemsetAsync(bnstats, 0, LAYERS * 2 * H * 4, stream);

    // CSR build
    hist_kernel<<<(N_EDGES + 255) / 256, 256, 0, stream>>>(dstIdx, cnt, N_EDGES);
    dinv_kernel<<<(N_NODES + 255) / 256, 256, 0, stream>>>(cnt, dinv, N_NODES);
    scan_kernel<<<1, 1024, 0, stream>>>(cnt, rowstart, N_NODES);
    fill_kernel<<<(N_EDGES + 255) / 256, 256, 0, stream>>>(srcIdx, dstIdx, rowstart, cursor,
                                                           dinv, csr_src, csr_w, N_EDGES);

    // casts: x -> bf16, weights -> transposed bf16
    cast_bf16_kernel<<<(N_NODES * XDIM + 255) / 256, 256, 0, stream>>>(x, xbf, N_NODES * XDIM);
    tcast_kernel<<<(XDIM * H + 255) / 256, 256, 0, stream>>>(encW, encWT, XDIM, H, 1);
    tcast_kernel<<<(LAYERS * H * H + 255) / 256, 256, 0, stream>>>(convW, convWT, H, H, LAYERS);

    // encoder: h = x @ encW + encB  (bf16 MFMA)
    dim3 gridG((N_NODES + 127) / 128, H / 128);
    gemm_bf16_kernel<XDIM><<<gridG, 256, 0, stream>>>(xbf, encWT, encB, hbf, N_NODES, H);

    // conv layers
    for (int l = 0; l < LAYERS; ++l) {
        gemm_bf16_kernel<H><<<gridG, 256, 0, stream>>>(hbf, convWT + (size_t)l * H * H, nullptr,
                                                       tbf, N_NODES, H);
        agg_kernel<<<N_NODES, H, 0, stream>>>(tbf, rowstart, csr_src, csr_w, dinv,
                                              convB + l * H, t2buf, N_NODES);
        stats_kernel<<<256, H, 0, stream>>>(t2buf, bnstats + l * 2 * H, N_NODES);
        bnrelu_kernel<<<512, H, 0, stream>>>(t2buf, bnstats + l * 2 * H,
                                             bnG + l * H, bnB + l * H, hbf, N_NODES);
    }

    // global mean pool
    pool_kernel<<<G_GRAPHS, H, 0, stream>>>(hbf, batch, gpool, N_NODES);

    // head (fp32, already fast)
    fc_lds_kernel<H, H><<<G_GRAPHS, 256, 0, stream>>>(gpool, fcW1, fcB1, m1);
    bn_head_kernel<<<H, G_GRAPHS, 0, stream>>>(m1, fcG1, fcBe1, m1, G_GRAPHS, 1);
    fc_lds_kernel<H, H><<<G_GRAPHS, 256, 0, stream>>>(m1, fcW2, fcB2, m2);
    bn_head_kernel<<<H, G_GRAPHS, 0, stream>>>(m2, fcG2, fcBe2, m2, G_GRAPHS, 0);
    fc_out_kernel<<<(G_GRAPHS * C_OUT + 255) / 256, 256, 0, stream>>>(m2, fcW3, fcB3, out);
}